// Round 2
// baseline (266.958 us; speedup 1.0000x reference)
//
#include <hip/hip_runtime.h>

// Problem: adjacency_full[i, neighbor_indices[i,k]] = adjacency_values[i,k]
// over a zeroed [N,N] fp32 matrix. N=8192, K=64.
//
// Strategy: write-BW bound (256 MiB out). Split into:
//   1) hipMemsetAsync zero-fill (rocclr fill kernel, measured 6.6 TB/s here)
//   2) scatter of 512K values (4 MiB coalesced reads, scattered 4B stores,
//      RMW absorbed by 256 MiB Infinity Cache)

constexpr int N_PATCH = 8192;
constexpr int K_NB = 64;
constexpr int TOTAL = N_PATCH * K_NB;  // 524288 scattered elements

__global__ __launch_bounds__(256)
void scatter_kernel(const float* __restrict__ vals,
                    const int* __restrict__ idx,
                    float* __restrict__ out) {
    const int f = blockIdx.x * 256 + threadIdx.x;  // flat (row, k)
    const int row = f >> 6;    // f / 64
    // coalesced reads: adjacent threads -> adjacent flat offsets
    const int col = idx[f];
    const float v = vals[f];
    out[(size_t)row * N_PATCH + col] = v;
}

extern "C" void kernel_launch(void* const* d_in, const int* in_sizes, int n_in,
                              void* d_out, int out_size, void* d_ws, size_t ws_size,
                              hipStream_t stream) {
    const float* vals = (const float*)d_in[0];   // adjacency_values [N,K] fp32
    const int* idx = (const int*)d_in[1];        // neighbor_indices [N,K] int32
    float* out = (float*)d_out;                  // [N,N] fp32

    // 1) zero the output with the tuned runtime fill (6.6 TB/s measured)
    hipMemsetAsync(out, 0, (size_t)out_size * sizeof(float), stream);

    // 2) scatter the 512K values (stream-ordered after the memset)
    scatter_kernel<<<TOTAL / 256, 256, 0, stream>>>(vals, idx, out);
}